// Round 2
// baseline (355.346 us; speedup 1.0000x reference)
//
#include <hip/hip_runtime.h>
#include <hip/hip_bf16.h>

// SpikingSelfAttention: T=4 B=32 C=384 N=256 NH=8 D=48
#define T_  4
#define B_  32
#define C_  384
#define N_  256
#define NH_ 8
#define D_  48
#define BN_ (B_*N_)
#define HEADELE (N_*D_)      // 12288 elements per (t,b,h)

typedef __attribute__((ext_vector_type(8))) short bf16x8;
typedef __attribute__((ext_vector_type(4))) float f32x4;

__device__ __forceinline__ float bf2f(unsigned short s) {
    return __uint_as_float(((unsigned int)s) << 16);
}
__device__ __forceinline__ unsigned short f2bf(float f) {
    __hip_bfloat16 h = __float2bfloat16(f);
    return __builtin_bit_cast(unsigned short, h);
}
__device__ __forceinline__ void unpack8(uint4 u, float* d) {
    d[0]=__uint_as_float((u.x&0xFFFFu)<<16); d[1]=__uint_as_float(u.x&0xFFFF0000u);
    d[2]=__uint_as_float((u.y&0xFFFFu)<<16); d[3]=__uint_as_float(u.y&0xFFFF0000u);
    d[4]=__uint_as_float((u.z&0xFFFFu)<<16); d[5]=__uint_as_float(u.z&0xFFFF0000u);
    d[6]=__uint_as_float((u.w&0xFFFFu)<<16); d[7]=__uint_as_float(u.w&0xFFFF0000u);
}
__device__ __forceinline__ void glds16(const void* g, void* l) {
    __builtin_amdgcn_global_load_lds(
        (const __attribute__((address_space(1))) void*)g,
        (__attribute__((address_space(3))) void*)l, 16, 0, 0);
}

// ---------------- K0: split fp32 weights into hi/lo bf16 ----------------
__global__ __launch_bounds__(256) void k_wsplit(const float* __restrict__ w0,
                                                const float* __restrict__ w1,
                                                const float* __restrict__ w2,
                                                unsigned short* __restrict__ hi,
                                                unsigned short* __restrict__ lo) {
    const float* w = (blockIdx.y==0) ? w0 : (blockIdx.y==1) ? w1 : w2;
    int i = (blockIdx.x*256 + threadIdx.x)*4;       // 144 blocks * 256 * 4 = 147456
    float4 f = *(const float4*)(w + i);
    ushort4 h, l;
    h.x=f2bf(f.x); l.x=f2bf(f.x - bf2f(h.x));
    h.y=f2bf(f.y); l.y=f2bf(f.y - bf2f(h.y));
    h.z=f2bf(f.z); l.z=f2bf(f.z - bf2f(h.z));
    h.w=f2bf(f.w); l.w=f2bf(f.w - bf2f(h.w));
    size_t o = (size_t)blockIdx.y*147456 + i;
    *(ushort4*)(hi + o) = h;
    *(ushort4*)(lo + o) = l;
}

// ---------------- K1: LIF over T on x; write spikes bf16 in [T][B][N][C] ----------------
__global__ __launch_bounds__(256) void k_lif1(const float* __restrict__ x,
                                              unsigned short* __restrict__ s0) {
    __shared__ unsigned short Tt[64*72];            // [n_local][c_local], padded row 72
    const int tid = threadIdx.x;
    const int b  = blockIdx.x;
    const int c0 = blockIdx.y * 64;
    const int n0 = blockIdx.z * 64;
    const int ci = tid >> 2;                        // 0..63
    const int nj = (tid & 3) * 16;
    float v[16];
    #pragma unroll
    for (int i=0;i<16;++i) v[i]=0.f;
    for (int t = 0; t < T_; ++t) {
        const float* xp = x + (((size_t)t*B_ + b)*C_ + c0 + ci)*N_ + n0 + nj;
        #pragma unroll
        for (int q=0;q<4;++q) {
            float4 f = *(const float4*)(xp + q*4);
            float e[4] = {f.x,f.y,f.z,f.w};
            #pragma unroll
            for (int j=0;j<4;++j) {
                int ii = q*4+j;
                float h = v[ii] + (e[j] - v[ii])*0.5f;
                bool sp = (h - 1.0f) >= 0.f;
                v[ii] = sp ? 0.f : h;
                Tt[(nj + ii)*72 + ci] = sp ? 0x3F80u : 0u;
            }
        }
        __syncthreads();
        int nrow = tid >> 2, cch = (tid & 3)*16;
        uint4 u0 = *(const uint4*)&Tt[nrow*72 + cch];
        uint4 u1 = *(const uint4*)&Tt[nrow*72 + cch + 8];
        unsigned short* gp = s0 + ((size_t)(t*B_ + b)*N_ + n0 + nrow)*C_ + c0 + cch;
        *(uint4*)gp = u0;
        *(uint4*)(gp + 8) = u1;
        __syncthreads();
    }
}

// ------------- K2: MFMA branch GEMM (Whi+Wlo) @ S + BN + LIF -> spikes [T][B][NH][N][D] -------------
struct Br2 {
    const unsigned short* whi[3];
    const unsigned short* wlo[3];
    const float *g[3], *be[3], *me[3], *va[3];
    __hip_bfloat16* out[3];
};

__global__ __launch_bounds__(256) void k_branch(const unsigned short* __restrict__ s0, Br2 a) {
    __shared__ unsigned short Wh[128*32];
    __shared__ unsigned short Wl[128*32];
    __shared__ unsigned short Sb[128*32];
    __shared__ float Ep[32*132];
    __shared__ float BNi[128], BNo[128];
    const int tid = threadIdx.x;
    const int z  = blockIdx.z;
    const int o0 = blockIdx.x * 128;
    const int b  = blockIdx.y >> 3;
    const int n0 = (blockIdx.y & 7) * 32;
    const int w    = tid >> 6;
    const int lane = tid & 63;
    const int quad = lane >> 4;
    const int lc   = lane & 15;
    const int mbase = (w >> 1) * 64;
    const int nbase = (w & 1) * 64;
    const unsigned short* __restrict__ Wgh = a.whi[z];
    const unsigned short* __restrict__ Wgl = a.wlo[z];

    if (tid < 128) {
        int o = o0 + tid;
        float inv = a.g[z][o] / sqrtf(a.va[z][o] + 1e-5f);
        BNi[tid] = inv;
        BNo[tid] = a.be[z][o] - a.me[z][o]*inv;
    }

    f32x4 acc[4][4];
    #pragma unroll
    for (int mt=0;mt<4;++mt)
        #pragma unroll
        for (int nt=0;nt<4;++nt) { acc[mt][nt][0]=0.f; acc[mt][nt][1]=0.f; acc[mt][nt][2]=0.f; acc[mt][nt][3]=0.f; }

    for (int ks = 0; ks < 12; ++ks) {
        const int k0 = ks*32;
        __syncthreads();
        #pragma unroll
        for (int j = 0; j < 2; ++j) {
            int row = w*32 + j*16 + (lane>>2);
            int p = lane & 3;
            int kcw = p ^ ((row>>1)&3);
            glds16(Wgh + (size_t)(o0+row)*C_ + k0 + kcw*8, &Wh[(w*32 + j*16)*32]);
            glds16(Wgl + (size_t)(o0+row)*C_ + k0 + kcw*8, &Wl[(w*32 + j*16)*32]);
            // S tile: wave w stages t=w, cols w*32 + [0,32)
            int nsw = j*16 + (lane>>2);
            int colw = w*32 + nsw;
            int kcs = p ^ ((colw>>1)&3);
            glds16(s0 + ((size_t)(w*B_ + b)*N_ + n0 + nsw)*C_ + k0 + kcs*8, &Sb[(w*32 + j*16)*32]);
        }
        __syncthreads();
        bf16x8 ah[4], al[4], bb[4];
        #pragma unroll
        for (int mt=0;mt<4;++mt) {
            int row = mbase + mt*16 + lc;
            int pc = quad ^ ((row>>1)&3);
            int off = row*32 + pc*8;
            ah[mt] = *(const bf16x8*)&Wh[off];
            al[mt] = *(const bf16x8*)&Wl[off];
        }
        #pragma unroll
        for (int nt=0;nt<4;++nt) {
            int col = nbase + nt*16 + lc;
            int pc = quad ^ ((col>>1)&3);
            bb[nt] = *(const bf16x8*)&Sb[col*32 + pc*8];
        }
        #pragma unroll
        for (int mt=0;mt<4;++mt)
            #pragma unroll
            for (int nt=0;nt<4;++nt) {
                acc[mt][nt] = __builtin_amdgcn_mfma_f32_16x16x32_bf16(ah[mt], bb[nt], acc[mt][nt], 0,0,0);
                acc[mt][nt] = __builtin_amdgcn_mfma_f32_16x16x32_bf16(al[mt], bb[nt], acc[mt][nt], 0,0,0);
            }
    }

    // epilogue: 4 rounds; round r handles o-rows {mbase + r*16 + [0,16)} for both halves
    __hip_bfloat16* out = a.out[z];
    const __hip_bfloat16 one = __float2bfloat16(1.0f), zero = __float2bfloat16(0.0f);
    for (int r = 0; r < 4; ++r) {
        __syncthreads();
        int erow = (w>>1)*16 + quad*4;
        #pragma unroll
        for (int nt=0;nt<4;++nt) {
            int col = (w&1)*64 + nt*16 + lc;
            Ep[(erow+0)*132 + col] = acc[r][nt][0];
            Ep[(erow+1)*132 + col] = acc[r][nt][1];
            Ep[(erow+2)*132 + col] = acc[r][nt][2];
            Ep[(erow+3)*132 + col] = acc[r][nt][3];
        }
        __syncthreads();
        int ns = tid & 31, ol = tid >> 5;
        #pragma unroll
        for (int cc=0; cc<4; ++cc) {
            int orow = ol + cc*8;                       // 0..31
            int oloc = ((orow & 16) ? 64 : 0) + r*16 + (orow & 15);
            int o = o0 + oloc;
            float inv = BNi[oloc], off = BNo[oloc];
            int hh = o / D_, dd = o - hh*D_;
            int n = n0 + ns;
            float v = 0.f;
            #pragma unroll
            for (int t=0;t<4;++t) {
                float y = Ep[orow*132 + t*32 + ns]*inv + off;
                float h = v + (y - v)*0.5f;
                bool sp = (h - 1.0f) >= 0.f;
                v = sp ? 0.f : h;
                out[(((size_t)(t*B_ + b)*NH_ + hh)*N_ + n)*D_ + dd] = sp ? one : zero;
            }
        }
    }
}

// ------------- K3: attention per (t,b,h): AO = Q (K^T V) * 0.125 (exact integers) -------------
__global__ __launch_bounds__(256) void k_attn(const __hip_bfloat16* __restrict__ qs,
                                              const __hip_bfloat16* __restrict__ ks,
                                              const __hip_bfloat16* __restrict__ vs,
                                              float* __restrict__ ao) {
    __shared__ unsigned short Kb[HEADELE];
    __shared__ unsigned short Vb[HEADELE];
    __shared__ float KtV[48][52];
    __shared__ int rowAny[256];
    __shared__ int mcnt;
    __shared__ int mlist[256];
    const int tid = threadIdx.x;
    const size_t base = (size_t)blockIdx.x * HEADELE;

    rowAny[tid] = 0;
    if (tid == 0) mcnt = 0;
    __syncthreads();

    const uint4* kp = (const uint4*)(ks + base);
    const uint4* vp = (const uint4*)(vs + base);
    unsigned int ka = 0, vaf = 0;
    #pragma unroll
    for (int i=0;i<6;++i) {
        int q = tid + i*256;
        uint4 u = kp[q];
        unsigned int nz = (u.x|u.y|u.z|u.w);
        ka |= nz;
        unsigned short* d = &Kb[q*8];
        d[0]=(unsigned short)(u.x&0xFFFFu); d[1]=(unsigned short)(u.x>>16);
        d[2]=(unsigned short)(u.y&0xFFFFu); d[3]=(unsigned short)(u.y>>16);
        d[4]=(unsigned short)(u.z&0xFFFFu); d[5]=(unsigned short)(u.z>>16);
        d[6]=(unsigned short)(u.w&0xFFFFu); d[7]=(unsigned short)(u.w>>16);
        if (nz) { int m0=(q*8)/D_, m1=(q*8+7)/D_; atomicOr(&rowAny[m0],1); if (m1!=m0) atomicOr(&rowAny[m1],1); }
        uint4 wv = vp[q];
        nz = (wv.x|wv.y|wv.z|wv.w);
        vaf |= nz;
        unsigned short* e = &Vb[q*8];
        e[0]=(unsigned short)(wv.x&0xFFFFu); e[1]=(unsigned short)(wv.x>>16);
        e[2]=(unsigned short)(wv.y&0xFFFFu); e[3]=(unsigned short)(wv.y>>16);
        e[4]=(unsigned short)(wv.z&0xFFFFu); e[5]=(unsigned short)(wv.z>>16);
        e[6]=(unsigned short)(wv.w&0xFFFFu); e[7]=(unsigned short)(wv.w>>16);
        if (nz) { int m0=(q*8)/D_, m1=(q*8+7)/D_; atomicOr(&rowAny[m0],2); if (m1!=m0) atomicOr(&rowAny[m1],2); }
    }
    int flags = __syncthreads_or((ka ? 1 : 0) | (vaf ? 2 : 0));
    float4 z4 = make_float4(0.f,0.f,0.f,0.f);
    if ((flags & 3) != 3) {
        float4* o4 = (float4*)(ao + base + (size_t)tid*D_);
        #pragma unroll
        for (int i=0;i<12;++i) o4[i] = z4;
        return;
    }
    if (rowAny[tid] == 3) mlist[atomicAdd(&mcnt, 1)] = tid;
    __syncthreads();

    const int dd1 = tid >> 2, gg = tid & 3;
    if (tid < 192) {
        float acc[12];
        #pragma unroll
        for (int i=0;i<12;++i) acc[i]=0.f;
        int cnt = mcnt;
        for (int ii=0; ii<cnt; ++ii) {
            int m = mlist[ii];
            if (Kb[m*D_ + dd1] != 0) {
                const unsigned short* vr = &Vb[m*D_ + gg*12];
                #pragma unroll
                for (int i=0;i<12;++i) acc[i] += bf2f(vr[i]);
            }
        }
        #pragma unroll
        for (int i=0;i<12;++i) KtV[dd1][gg*12+i] = acc[i];
    }
    __syncthreads();

    float qf[48];
    const uint4* qp = (const uint4*)(qs + base + (size_t)tid*D_);
    unsigned int qa = 0;
    #pragma unroll
    for (int i=0;i<6;++i) { uint4 u = qp[i]; qa |= (u.x|u.y|u.z|u.w); unpack8(u, &qf[i*8]); }
    float* aout = ao + base + (size_t)tid*D_;
    if (!qa) {
        float4* o4 = (float4*)aout;
        #pragma unroll
        for (int i=0;i<12;++i) o4[i] = z4;
        return;
    }
    float oc[48];
    #pragma unroll
    for (int i=0;i<48;++i) oc[i]=0.f;
    for (int d1=0; d1<48; ++d1) {
        if (qf[d1] != 0.f) {
            const float* kt = &KtV[d1][0];
            #pragma unroll
            for (int i=0;i<48;++i) oc[i] += kt[i];
        }
    }
    float4* o4 = (float4*)aout;
    #pragma unroll
    for (int i=0;i<12;++i)
        o4[i] = make_float4(oc[i*4]*0.125f, oc[i*4+1]*0.125f, oc[i*4+2]*0.125f, oc[i*4+3]*0.125f);
}

// ---------------- K4: attn LIF over T ----------------
__global__ __launch_bounds__(256) void k_lif3(const float* __restrict__ ao,
                                              __hip_bfloat16* __restrict__ s2) {
    size_t idx = (size_t)blockIdx.x*256 + threadIdx.x;
    const __hip_bfloat16 one = __float2bfloat16(1.0f), zero = __float2bfloat16(0.0f);
    float v = 0.f;
    #pragma unroll
    for (int t=0;t<T_;++t) {
        float xv = ao[(size_t)t*3145728 + idx];
        float h = v + (xv - v)*0.5f;
        bool sp = (h - 1.0f) >= 0.f;
        v = sp ? 0.f : h;
        s2[(size_t)t*3145728 + idx] = sp ? one : zero;
    }
}

#define FMA8(A, wgt, sA, sB) \
    A[0] += (wgt)*(sA).x; A[1] += (wgt)*(sA).y; A[2] += (wgt)*(sA).z; A[3] += (wgt)*(sA).w; \
    A[4] += (wgt)*(sB).x; A[5] += (wgt)*(sB).y; A[6] += (wgt)*(sB).z; A[7] += (wgt)*(sB).w;

// ---------------- K5: proj GEMM + bias + BN -> out [T][B][C][N] fp32 ----------------
__global__ __launch_bounds__(256) void k_proj(const __hip_bfloat16* __restrict__ s2,
        const float* __restrict__ W, const float* __restrict__ pb,
        const float* __restrict__ g, const float* __restrict__ be,
        const float* __restrict__ me, const float* __restrict__ va,
        float* __restrict__ out) {
    __shared__ float Wt[48][132];
    __shared__ float St[48][132];
    const int tid = threadIdx.x;
    const int o0 = blockIdx.x * 128;
    const int b  = blockIdx.y >> 3;
    const int n0 = (blockIdx.y & 7) * 32;
    const unsigned short* __restrict__ S = (const unsigned short*)s2;

    float a0[4][8], a1[4][8];
    for (int t=0;t<4;++t)
        for (int i=0;i<8;++i){ a0[t][i]=0.f; a1[t][i]=0.f; }

    const int oa = tid & 63, ob = oa + 64;
    const int ng = tid >> 6;
    const int cb = ng * 8;
    const int wo = tid >> 1;
    const int wk = (tid & 1) * 24;

    for (int hh = 0; hh < NH_; ++hh) {
        const float* wp = W + (size_t)(o0 + wo)*C_ + hh*D_ + wk;
        #pragma unroll
        for (int i=0;i<6;++i) {
            float4 f = *(const float4*)(wp + i*4);
            Wt[wk+i*4+0][wo]=f.x; Wt[wk+i*4+1][wo]=f.y;
            Wt[wk+i*4+2][wo]=f.z; Wt[wk+i*4+3][wo]=f.w;
        }
        unsigned int anyv = 0;
        #pragma unroll
        for (int i=0;i<3;++i) {
            int q = tid + i*256;
            int t = q / 192, rem = q - t*192;
            int ns = rem / 6, c8 = rem - ns*6;
            const uint4* p = (const uint4*)(S + ((((size_t)t*B_ + b)*NH_ + hh)*N_ + n0 + ns)*D_ + c8*8);
            uint4 u = *p;
            anyv |= (u.x|u.y|u.z|u.w);
            float f8[8]; unpack8(u, f8);
            #pragma unroll
            for (int j=0;j<8;++j) St[c8*8+j][t*32+ns] = f8[j];
        }
        int any = __syncthreads_or((int)(anyv != 0u));
        if (any) {
            #pragma unroll 4
            for (int kk=0; kk<48; ++kk) {
                float w0 = Wt[kk][oa], w1 = Wt[kk][ob];
                #pragma unroll
                for (int t=0;t<4;++t) {
                    const float4 sA = *(const float4*)&St[kk][t*32+cb];
                    const float4 sB = *(const float4*)&St[kk][t*32+cb+4];
                    FMA8(a0[t], w0, sA, sB)
                    FMA8(a1[t], w1, sA, sB)
                }
            }
        }
        __syncthreads();
    }
    #pragma unroll
    for (int j=0;j<2;++j) {
        int o = o0 + (j ? ob : oa);
        float inv = g[o] / sqrtf(va[o] + 1e-5f);
        float off = be[o] - me[o]*inv;
        float bias = pb[o];
        #pragma unroll
        for (int t=0;t<4;++t) {
            float r[8];
            #pragma unroll
            for (int i=0;i<8;++i) r[i] = ((j ? a1[t][i] : a0[t][i]) + bias)*inv + off;
            float* op = out + (((size_t)t*B_ + b)*C_ + o)*N_ + n0 + cb;
            *(float4*)op       = make_float4(r[0],r[1],r[2],r[3]);
            *(float4*)(op + 4) = make_float4(r[4],r[5],r[6],r[7]);
        }
    }
}

extern "C" void kernel_launch(void* const* d_in, const int* in_sizes, int n_in,
                              void* d_out, int out_size, void* d_ws, size_t ws_size,
                              hipStream_t stream) {
    const float* x  = (const float*)d_in[0];
    char* ws = (char*)d_ws;
    // ws: S0 [0,25165824) | Q/K/V 3x25165824 | AO fp32 50331648 (Whi/Wlo live at AO base
    // during k_wsplit..k_branch; k_attn overwrites later). S2 reuses S0.
    unsigned short* S0 = (unsigned short*)ws;
    __hip_bfloat16* Q  = (__hip_bfloat16*)(ws + 25165824);
    __hip_bfloat16* K  = (__hip_bfloat16*)(ws + 50331648);
    __hip_bfloat16* V  = (__hip_bfloat16*)(ws + 75497472);
    float*          AO = (float*)(ws + 100663296);
    unsigned short* WHI = (unsigned short*)(ws + 100663296);
    unsigned short* WLO = WHI + 3*147456;
    __hip_bfloat16* S2 = (__hip_bfloat16*)ws;

    k_wsplit<<<dim3(144,3), 256, 0, stream>>>(
        (const float*)d_in[2], (const float*)d_in[7], (const float*)d_in[12], WHI, WLO);

    k_lif1<<<dim3(32,6,4), 256, 0, stream>>>(x, S0);

    Br2 ba;
    for (int z=0;z<3;++z) { ba.whi[z] = WHI + z*147456; ba.wlo[z] = WLO + z*147456; }
    ba.g[0]=(const float*)d_in[3];  ba.be[0]=(const float*)d_in[4];
    ba.me[0]=(const float*)d_in[5]; ba.va[0]=(const float*)d_in[6];
    ba.g[1]=(const float*)d_in[8];  ba.be[1]=(const float*)d_in[9];
    ba.me[1]=(const float*)d_in[10]; ba.va[1]=(const float*)d_in[11];
    ba.g[2]=(const float*)d_in[13]; ba.be[2]=(const float*)d_in[14];
    ba.me[2]=(const float*)d_in[15]; ba.va[2]=(const float*)d_in[16];
    ba.out[0]=Q; ba.out[1]=K; ba.out[2]=V;
    k_branch<<<dim3(3, 256, 3), 256, 0, stream>>>(S0, ba);

    k_attn<<<T_*B_*NH_, 256, 0, stream>>>(Q, K, V, AO);
    k_lif3<<<12288, 256, 0, stream>>>(AO, S2);
    k_proj<<<dim3(3, 256), 256, 0, stream>>>(S2,
        (const float*)d_in[17], (const float*)d_in[18],
        (const float*)d_in[19], (const float*)d_in[20],
        (const float*)d_in[21], (const float*)d_in[22],
        (float*)d_out);
}